// Round 24
// baseline (35.630 us; speedup 1.0000x reference)
//
#include <hip/hip_runtime.h>
#include <math.h>

#define NN 2048
#define EE 1024

typedef unsigned long long ull;
typedef unsigned short ushortt;

// ---------------------------------------------------------------------------
// D1 k_scan (grid 576 x 512 threads): three jobs by block range.
//   [0,64)     cscan : 16 cols/block (each 64B H-line fetched ONCE per
//                      16-col group) via 4x float4; 8 waves x 256-row segs;
//                      cbuf ALIASED into smem (LDS stays 35KB)
//   [64,320)   rfill : 8 rows/block, 1 row/wave, float4 (4 ballot rounds)
//   [320,576)  npb   : node projection npb = x @ W1[:, :64]^T + b1 (8 rows)
// ---------------------------------------------------------------------------
__global__ __launch_bounds__(512)
void k_scan(const float* __restrict__ H, const float* __restrict__ x,
            const float* __restrict__ W1, const float* __restrict__ b1,
            ushortt* __restrict__ elist, int* __restrict__ cnt,
            float* __restrict__ dn,
            ushortt* __restrict__ clist, int* __restrict__ ccnt,
            float* __restrict__ de,
            float* __restrict__ npb) {
  __shared__ __align__(16) float smem[64 * 129 + 8 * 64];
  int bid = blockIdx.x, t = threadIdx.x, wv = t >> 6, lane = t & 63;
  ull below = (1ull << lane) - 1ull;
  if (bid < 64) {
    // ---- cscan: 16 cols/block; wave wv scans rows [wv*256, wv*256+256)
    ushortt* cbuf = (ushortt*)smem;                    // [8][16][64] = 16384 B
    int* csh = (int*)((char*)smem + 16384);            // [8][16] = 512 B
    int e0 = bid * 16;
    int cs[16];
    #pragma unroll
    for (int col = 0; col < 16; ++col) cs[col] = 0;
    #pragma unroll
    for (int it = 0; it < 4; ++it) {
      int r = wv * 256 + it * 64 + lane;
      const float* hr = &H[(size_t)r * EE + e0];
      float4 h0 = *(const float4*)&hr[0];
      float4 h1 = *(const float4*)&hr[4];
      float4 h2 = *(const float4*)&hr[8];
      float4 h3 = *(const float4*)&hr[12];
      float va[16] = {h0.x, h0.y, h0.z, h0.w, h1.x, h1.y, h1.z, h1.w,
                      h2.x, h2.y, h2.z, h2.w, h3.x, h3.y, h3.z, h3.w};
      #pragma unroll
      for (int col = 0; col < 16; ++col) {
        ull m = __ballot(va[col] != 0.f);
        int pos = cs[col] + __popcll(m & below);
        if (va[col] != 0.f && pos < 64)
          cbuf[(wv * 16 + col) * 64 + pos] = (ushortt)r;
        cs[col] += __popcll(m);
      }
    }
    if (lane == 0) {
      #pragma unroll
      for (int col = 0; col < 16; ++col) csh[wv * 16 + col] = cs[col];
    }
    __syncthreads();
    // merge: wave wv owns columns 2*wv and 2*wv+1
    #pragma unroll
    for (int cc2 = 0; cc2 < 2; ++cc2) {
      int col = wv * 2 + cc2, e = e0 + col;
      int base = 0, total = 0;
      #pragma unroll
      for (int u = 0; u < 8; ++u) {
        int cu = csh[u * 16 + col];
        int cc = min(cu, 64);
        for (int i = lane; i < cc; i += 64) {
          int p = base + i;
          if (p < 192) clist[e * 192 + p] = cbuf[(u * 16 + col) * 64 + i];
        }
        base += cc;
        total += cu;
      }
      if (lane == 0) {
        ccnt[e] = total;
        de[e] = total ? 1.f / (float)total : 0.f;
      }
    }
  } else if (bid < 320) {
    // ---- rfill: 1 row per wave, float4 (each H-line read once)
    int n = (bid - 64) * 8 + wv;
    const float* row = H + (size_t)n * EE;
    int count = 0;
    #pragma unroll
    for (int it = 0; it < 4; ++it) {
      float4 hv = *(const float4*)&row[it * 256 + lane * 4];
      float va[4] = {hv.x, hv.y, hv.z, hv.w};
      ull m[4];
      #pragma unroll
      for (int c2 = 0; c2 < 4; ++c2) m[c2] = __ballot(va[c2] != 0.f);
      int rl = 0;
      #pragma unroll
      for (int c2 = 0; c2 < 4; ++c2) rl += __popcll(m[c2] & below);
      int within = 0;
      #pragma unroll
      for (int c2 = 0; c2 < 4; ++c2) {
        if (va[c2] != 0.f) {
          int pos = count + rl + within;
          if (pos < 128) elist[n * 128 + pos] = (ushortt)(it * 256 + lane * 4 + c2);
          ++within;
        }
      }
      #pragma unroll
      for (int c2 = 0; c2 < 4; ++c2) count += __popcll(m[c2]);
    }
    if (lane == 0) {
      cnt[n] = count;
      dn[n] = count ? rsqrtf((float)count) : 0.f;
    }
  } else {
    // ---- npb: 8 rows x 128 h; W1 node-half transposed in LDS
    float* Wt = smem;
    float* xl = smem + 64 * 129;
    int r0 = (bid - 320) * 8;
    #pragma unroll
    for (int p = 0; p < 16; ++p) {
      int j = t + p * 512;
      int h = j >> 6, d = j & 63;
      Wt[d * 129 + h] = W1[h * 128 + d];
    }
    {
      int r = t >> 6, d = t & 63;
      xl[r * 64 + d] = x[(size_t)(r0 + r) * 64 + d];
    }
    __syncthreads();
    #pragma unroll
    for (int k = 0; k < 2; ++k) {
      int idx = t + k * 512;
      int row = idx >> 7, h = idx & 127;
      float acc = b1[h];
      #pragma unroll 8
      for (int d = 0; d < 64; ++d)
        acc += xl[row * 64 + d] * Wt[d * 129 + h];
      npb[(size_t)(r0 + row) * 128 + h] = acc;
    }
  }
}

// ---------------------------------------------------------------------------
// D2 k_edge (grid EE x 512): R22 proven structure unchanged.
// ---------------------------------------------------------------------------
__global__ __launch_bounds__(512)
void k_edge(const ushortt* __restrict__ clist,
            const int* __restrict__ ccnt, const float* __restrict__ de,
            const float* __restrict__ dn, const float* __restrict__ x,
            const float* __restrict__ W1, const float* __restrict__ npb,
            const float* __restrict__ W2, const float* __restrict__ b2,
            float* __restrict__ sigc, float* __restrict__ w) {
  __shared__ __align__(16) float Wt[64 * 129];
  __shared__ __align__(16) float psum[8][64];
  __shared__ __align__(16) float efl[64];
  __shared__ __align__(16) float epl[128];
  __shared__ __align__(16) float pp[4][128];
  __shared__ __align__(16) float w2l[128];
  __shared__ __align__(16) float sval[192];
  __shared__ __align__(16) ushortt cls[192];
  int t = threadIdx.x, wv = t >> 6, lane = t & 63;
  int e = blockIdx.x;
  int c = min(ccnt[e], 192);
  #pragma unroll
  for (int p = 0; p < 16; ++p) {
    int j = t + p * 512;
    int h = j >> 6, d = j & 63;
    Wt[d * 129 + h] = W1[h * 128 + 64 + d];
  }
  if (t < 128) w2l[t] = W2[t];
  if (t < 96) ((uint*)cls)[t] = ((const uint*)(clist + (size_t)e * 192))[t];
  __syncthreads();
  // pass 1: ef gather, tiered 8/4/1-deep batching
  {
    float a0 = 0.f, a1 = 0.f, a2 = 0.f, a3 = 0.f;
    int j = wv;
    for (; j + 56 < c; j += 64) {
      int n0 = cls[j], n1 = cls[j + 8], n2 = cls[j + 16], n3 = cls[j + 24];
      int n4 = cls[j + 32], n5 = cls[j + 40], n6 = cls[j + 48], n7 = cls[j + 56];
      a0 += x[(size_t)n0 * 64 + lane];
      a1 += x[(size_t)n1 * 64 + lane];
      a2 += x[(size_t)n2 * 64 + lane];
      a3 += x[(size_t)n3 * 64 + lane];
      a0 += x[(size_t)n4 * 64 + lane];
      a1 += x[(size_t)n5 * 64 + lane];
      a2 += x[(size_t)n6 * 64 + lane];
      a3 += x[(size_t)n7 * 64 + lane];
    }
    for (; j + 24 < c; j += 32) {
      int n0 = cls[j], n1 = cls[j + 8], n2 = cls[j + 16], n3 = cls[j + 24];
      a0 += x[(size_t)n0 * 64 + lane];
      a1 += x[(size_t)n1 * 64 + lane];
      a2 += x[(size_t)n2 * 64 + lane];
      a3 += x[(size_t)n3 * 64 + lane];
    }
    for (; j < c; j += 8) a0 += x[(size_t)cls[j] * 64 + lane];
    psum[wv][lane] = (a0 + a1) + (a2 + a3);
  }
  __syncthreads();
  if (wv == 0) {
    float s = 0.f;
    #pragma unroll
    for (int u = 0; u < 8; ++u) s += psum[u][lane];
    efl[lane] = s;
  }
  __syncthreads();
  // projection: 512 threads = 128 h x 4 d-quarters (Wt from LDS)
  {
    int h = t & 127, q = t >> 7;
    float a = 0.f;
    #pragma unroll
    for (int d = q * 16; d < q * 16 + 16; ++d)
      a += efl[d] * Wt[d * 129 + h];
    pp[q][h] = a;
  }
  __syncthreads();
  if (t < 128) epl[t] = pp[0][t] + pp[1][t] + pp[2][t] + pp[3][t];
  __syncthreads();
  // batched scores: 128 entries x 4 subs (32 h each); sigma -> sigc column
  {
    int sub = t & 3, jloc = t >> 2;
    float b2v = b2[0];
    int nb = (c + 127) >> 7;
    for (int b = 0; b < nb; ++b) {
      int j = b * 128 + jloc;
      if (j < c) {
        int n = cls[j];
        const float* npr = npb + (size_t)n * 128;
        float a = 0.f;
        #pragma unroll
        for (int q = 0; q < 8; ++q) {
          int o = q * 16 + sub * 4;
          float4 av = *(const float4*)&npr[o];
          float4 ev = *(const float4*)&epl[o];
          float4 w2 = *(const float4*)&w2l[o];
          a += fmaxf(av.x + ev.x, 0.f) * w2.x + fmaxf(av.y + ev.y, 0.f) * w2.y
             + fmaxf(av.z + ev.z, 0.f) * w2.z + fmaxf(av.w + ev.w, 0.f) * w2.w;
        }
        a += __shfl_xor(a, 1, 64);
        a += __shfl_xor(a, 2, 64);
        if (sub == 0) {
          float sg = 1.f / (1.f + __expf(-(a + b2v)));
          sval[j] = dn[n] * sg;
          sigc[(size_t)e * NN + n] = sg;   // block-local lines only
        }
      }
    }
  }
  __syncthreads();
  // pass 2: weighted gather, tiered 8/4/1-deep batching
  {
    float a0 = 0.f, a1 = 0.f, a2 = 0.f, a3 = 0.f;
    int j = wv;
    for (; j + 56 < c; j += 64) {
      int n0 = cls[j], n1 = cls[j + 8], n2 = cls[j + 16], n3 = cls[j + 24];
      int n4 = cls[j + 32], n5 = cls[j + 40], n6 = cls[j + 48], n7 = cls[j + 56];
      a0 += sval[j] * x[(size_t)n0 * 64 + lane];
      a1 += sval[j + 8] * x[(size_t)n1 * 64 + lane];
      a2 += sval[j + 16] * x[(size_t)n2 * 64 + lane];
      a3 += sval[j + 24] * x[(size_t)n3 * 64 + lane];
      a0 += sval[j + 32] * x[(size_t)n4 * 64 + lane];
      a1 += sval[j + 40] * x[(size_t)n5 * 64 + lane];
      a2 += sval[j + 48] * x[(size_t)n6 * 64 + lane];
      a3 += sval[j + 56] * x[(size_t)n7 * 64 + lane];
    }
    for (; j + 24 < c; j += 32) {
      int n0 = cls[j], n1 = cls[j + 8], n2 = cls[j + 16], n3 = cls[j + 24];
      a0 += sval[j] * x[(size_t)n0 * 64 + lane];
      a1 += sval[j + 8] * x[(size_t)n1 * 64 + lane];
      a2 += sval[j + 16] * x[(size_t)n2 * 64 + lane];
      a3 += sval[j + 24] * x[(size_t)n3 * 64 + lane];
    }
    for (; j < c; j += 8) a0 += sval[j] * x[(size_t)cls[j] * 64 + lane];
    psum[wv][lane] = (a0 + a1) + (a2 + a3);
  }
  __syncthreads();
  if (wv == 0) {
    float s = 0.f;
    #pragma unroll
    for (int u = 0; u < 8; ++u) s += psum[u][lane];
    w[(size_t)e * 64 + lane] = de[e] * s;
  }
}

// ---------------------------------------------------------------------------
// D3 k_node (grid NN/2 x 512): R22 proven structure unchanged.
// ---------------------------------------------------------------------------
__global__ __launch_bounds__(512)
void k_node(const ushortt* __restrict__ elist, const int* __restrict__ cnt,
            const float* __restrict__ dn, const float* __restrict__ sigc,
            const float* __restrict__ w,
            const float* __restrict__ Wlg, const float* __restrict__ bl,
            float* __restrict__ out) {
  __shared__ __align__(16) float Wlds[64 * 65];
  __shared__ __align__(16) float sval[2][128];
  __shared__ __align__(16) float psum[8][64];
  __shared__ __align__(16) float zl[2][64];
  __shared__ __align__(16) ushortt els[2][128];
  int t = threadIdx.x, wv = t >> 6, lane = t & 63;
  int n0 = blockIdx.x * 2;
  #pragma unroll
  for (int p = 0; p < 8; ++p) {
    int j = t + p * 512;
    Wlds[(j >> 6) * 65 + (j & 63)] = Wlg[j];
  }
  if (t < 128) ((uint*)els)[t] = ((const uint*)(elist + (size_t)n0 * 128))[t];
  __syncthreads();
  // sigma gather: one independent load per entry
  if (t < 256) {
    int nd = t >> 7, jj = t & 127;
    int n = n0 + nd;
    int c = min(cnt[n], 128);
    if (jj < c) {
      int e = els[nd][jj];
      sval[nd][jj] = sigc[(size_t)e * NN + n];
    }
  }
  __syncthreads();
  // z gather: waves 0-3 node 0, 4-7 node 1; tiered 8/4/1-deep batching
  {
    int nd = wv >> 2;
    int n = n0 + nd;
    int c = min(cnt[n], 128);
    float a0 = 0.f, a1 = 0.f, a2 = 0.f, a3 = 0.f;
    int j = wv & 3;
    for (; j + 28 < c; j += 32) {
      int e0 = els[nd][j], e1 = els[nd][j + 4], e2 = els[nd][j + 8], e3 = els[nd][j + 12];
      int e4 = els[nd][j + 16], e5 = els[nd][j + 20], e6 = els[nd][j + 24], e7 = els[nd][j + 28];
      a0 += sval[nd][j] * w[(size_t)e0 * 64 + lane];
      a1 += sval[nd][j + 4] * w[(size_t)e1 * 64 + lane];
      a2 += sval[nd][j + 8] * w[(size_t)e2 * 64 + lane];
      a3 += sval[nd][j + 12] * w[(size_t)e3 * 64 + lane];
      a0 += sval[nd][j + 16] * w[(size_t)e4 * 64 + lane];
      a1 += sval[nd][j + 20] * w[(size_t)e5 * 64 + lane];
      a2 += sval[nd][j + 24] * w[(size_t)e6 * 64 + lane];
      a3 += sval[nd][j + 28] * w[(size_t)e7 * 64 + lane];
    }
    for (; j + 12 < c; j += 16) {
      int e0 = els[nd][j], e1 = els[nd][j + 4], e2 = els[nd][j + 8], e3 = els[nd][j + 12];
      a0 += sval[nd][j] * w[(size_t)e0 * 64 + lane];
      a1 += sval[nd][j + 4] * w[(size_t)e1 * 64 + lane];
      a2 += sval[nd][j + 8] * w[(size_t)e2 * 64 + lane];
      a3 += sval[nd][j + 12] * w[(size_t)e3 * 64 + lane];
    }
    for (; j < c; j += 4) a0 += sval[nd][j] * w[(size_t)els[nd][j] * 64 + lane];
    psum[wv][lane] = (a0 + a1) + (a2 + a3);
    __syncthreads();
    if ((wv & 3) == 0)
      zl[nd][lane] = dn[n] * (psum[wv][lane] + psum[wv + 1][lane] +
                              psum[wv + 2][lane] + psum[wv + 3][lane]);
  }
  __syncthreads();
  {
    float* pp = (float*)psum;
    int o = t & 63, nd = (t >> 6) & 1, q = t >> 7;
    float po = 0.f;
    #pragma unroll
    for (int d = q * 16; d < q * 16 + 16; ++d)
      po += zl[nd][d] * Wlds[o * 65 + d];
    pp[q * 128 + nd * 64 + o] = po;
    __syncthreads();
    if (t < 128) {
      int ndo = t >> 6, oo = t & 63;
      out[(size_t)(n0 + ndo) * 64 + oo] =
          bl[oo] + pp[0 * 128 + t] + pp[1 * 128 + t] + pp[2 * 128 + t] + pp[3 * 128 + t];
    }
  }
}

extern "C" void kernel_launch(void* const* d_in, const int* in_sizes, int n_in,
                              void* d_out, int out_size, void* d_ws, size_t ws_size,
                              hipStream_t stream) {
  const float* x  = (const float*)d_in[0];
  const float* H  = (const float*)d_in[1];
  const float* W1 = (const float*)d_in[2];
  const float* b1 = (const float*)d_in[3];
  const float* W2 = (const float*)d_in[4];
  const float* b2 = (const float*)d_in[5];
  const float* Wl = (const float*)d_in[6];
  const float* bl = (const float*)d_in[7];
  float* out = (float*)d_out;

  char* wsb = (char*)d_ws;
  float* dn   = (float*)wsb;  wsb += NN * 4;
  float* de   = (float*)wsb;  wsb += EE * 4;
  int*   cnt  = (int*)wsb;    wsb += NN * 4;
  int*   ccnt = (int*)wsb;    wsb += EE * 4;
  float* npb  = (float*)wsb;  wsb += (size_t)NN * 128 * 4;
  float* w    = (float*)wsb;  wsb += (size_t)EE * 64 * 4;
  float* sigc = (float*)wsb;  wsb += (size_t)EE * NN * 4;  // nnz-only, col-major
  ushortt* elist = (ushortt*)wsb; wsb += (size_t)NN * 128 * 2;
  ushortt* clist = (ushortt*)wsb; wsb += (size_t)EE * 192 * 2;

  hipLaunchKernelGGL(k_scan, dim3(576), dim3(512), 0, stream,
                     H, x, W1, b1, elist, cnt, dn, clist, ccnt, de, npb);
  hipLaunchKernelGGL(k_edge, dim3(EE), dim3(512), 0, stream,
                     clist, ccnt, de, dn, x, W1, npb, W2, b2, sigc, w);
  hipLaunchKernelGGL(k_node, dim3(NN / 2), dim3(512), 0, stream,
                     elist, cnt, dn, sigc, w, Wl, bl, out);
}

// Round 25
// 34.972 us; speedup vs baseline: 1.0188x; 1.0188x over previous
//
#include <hip/hip_runtime.h>
#include <math.h>

#define NN 2048
#define EE 1024

typedef unsigned long long ull;
typedef unsigned short ushortt;

// ---------------------------------------------------------------------------
// D1 k_scan (grid 640 x 512 threads): three jobs by block range.
//   [0,128)    cscan : 8 cols/block via 2x float4; 8 waves x 256-row segments
//              (R23 optimum: R24's 16-col variant regressed -- 16 serialized
//               ballots/iter + 64-block parallelism loss > line-touch saving)
//   [128,384)  rfill : 8 rows/block, 1 row/wave, float4 (4 ballot rounds)
//   [384,640)  npb   : node projection npb = x @ W1[:, :64]^T + b1 (8 rows)
// ---------------------------------------------------------------------------
__global__ __launch_bounds__(512)
void k_scan(const float* __restrict__ H, const float* __restrict__ x,
            const float* __restrict__ W1, const float* __restrict__ b1,
            ushortt* __restrict__ elist, int* __restrict__ cnt,
            float* __restrict__ dn,
            ushortt* __restrict__ clist, int* __restrict__ ccnt,
            float* __restrict__ de,
            float* __restrict__ npb) {
  __shared__ __align__(16) float smem[64 * 129 + 8 * 64];
  __shared__ ushortt cbuf[8][8][64];    // [segment-wave][col][pos]
  __shared__ int csh[8][8];
  int bid = blockIdx.x, t = threadIdx.x, wv = t >> 6, lane = t & 63;
  ull below = (1ull << lane) - 1ull;
  if (bid < 128) {
    // ---- cscan: 8 cols/block; wave wv scans rows [wv*256, wv*256+256)
    int e0 = bid * 8;
    int cs[8] = {0, 0, 0, 0, 0, 0, 0, 0};
    #pragma unroll
    for (int it = 0; it < 4; ++it) {
      int r = wv * 256 + it * 64 + lane;
      float4 h0 = *(const float4*)&H[(size_t)r * EE + e0];
      float4 h1 = *(const float4*)&H[(size_t)r * EE + e0 + 4];
      float va[8] = {h0.x, h0.y, h0.z, h0.w, h1.x, h1.y, h1.z, h1.w};
      #pragma unroll
      for (int col = 0; col < 8; ++col) {
        ull m = __ballot(va[col] != 0.f);
        int pos = cs[col] + __popcll(m & below);
        if (va[col] != 0.f && pos < 64) cbuf[wv][col][pos] = (ushortt)r;
        cs[col] += __popcll(m);
      }
    }
    if (lane == 0) {
      #pragma unroll
      for (int col = 0; col < 8; ++col) csh[wv][col] = cs[col];
    }
    __syncthreads();
    // merge: wave wv owns column wv (segments already row-ascending)
    {
      int col = wv, e = e0 + col;
      int base = 0, total = 0;
      #pragma unroll
      for (int u = 0; u < 8; ++u) {
        int cu = csh[u][col];
        int cc = min(cu, 64);
        for (int i = lane; i < cc; i += 64) {
          int p = base + i;
          if (p < 192) clist[e * 192 + p] = cbuf[u][col][i];
        }
        base += cc;
        total += cu;
      }
      if (lane == 0) {
        ccnt[e] = total;
        de[e] = total ? 1.f / (float)total : 0.f;
      }
    }
  } else if (bid < 384) {
    // ---- rfill: 1 row per wave, float4 (each H-line read once)
    int n = (bid - 128) * 8 + wv;
    const float* row = H + (size_t)n * EE;
    int count = 0;
    #pragma unroll
    for (int it = 0; it < 4; ++it) {
      float4 hv = *(const float4*)&row[it * 256 + lane * 4];
      float va[4] = {hv.x, hv.y, hv.z, hv.w};
      ull m[4];
      #pragma unroll
      for (int c2 = 0; c2 < 4; ++c2) m[c2] = __ballot(va[c2] != 0.f);
      int rl = 0;
      #pragma unroll
      for (int c2 = 0; c2 < 4; ++c2) rl += __popcll(m[c2] & below);
      int within = 0;
      #pragma unroll
      for (int c2 = 0; c2 < 4; ++c2) {
        if (va[c2] != 0.f) {
          int pos = count + rl + within;
          if (pos < 128) elist[n * 128 + pos] = (ushortt)(it * 256 + lane * 4 + c2);
          ++within;
        }
      }
      #pragma unroll
      for (int c2 = 0; c2 < 4; ++c2) count += __popcll(m[c2]);
    }
    if (lane == 0) {
      cnt[n] = count;
      dn[n] = count ? rsqrtf((float)count) : 0.f;
    }
  } else {
    // ---- npb: 8 rows x 128 h; W1 node-half transposed in LDS
    float* Wt = smem;
    float* xl = smem + 64 * 129;
    int r0 = (bid - 384) * 8;
    #pragma unroll
    for (int p = 0; p < 16; ++p) {
      int j = t + p * 512;
      int h = j >> 6, d = j & 63;
      Wt[d * 129 + h] = W1[h * 128 + d];
    }
    {
      int r = t >> 6, d = t & 63;
      xl[r * 64 + d] = x[(size_t)(r0 + r) * 64 + d];
    }
    __syncthreads();
    #pragma unroll
    for (int k = 0; k < 2; ++k) {
      int idx = t + k * 512;
      int row = idx >> 7, h = idx & 127;
      float acc = b1[h];
      #pragma unroll 8
      for (int d = 0; d < 64; ++d)
        acc += xl[row * 64 + d] * Wt[d * 129 + h];
      npb[(size_t)(r0 + row) * 128 + h] = acc;
    }
  }
}

// ---------------------------------------------------------------------------
// D2 k_edge (grid EE x 512): R22 proven structure unchanged.
// ---------------------------------------------------------------------------
__global__ __launch_bounds__(512)
void k_edge(const ushortt* __restrict__ clist,
            const int* __restrict__ ccnt, const float* __restrict__ de,
            const float* __restrict__ dn, const float* __restrict__ x,
            const float* __restrict__ W1, const float* __restrict__ npb,
            const float* __restrict__ W2, const float* __restrict__ b2,
            float* __restrict__ sigc, float* __restrict__ w) {
  __shared__ __align__(16) float Wt[64 * 129];
  __shared__ __align__(16) float psum[8][64];
  __shared__ __align__(16) float efl[64];
  __shared__ __align__(16) float epl[128];
  __shared__ __align__(16) float pp[4][128];
  __shared__ __align__(16) float w2l[128];
  __shared__ __align__(16) float sval[192];
  __shared__ __align__(16) ushortt cls[192];
  int t = threadIdx.x, wv = t >> 6, lane = t & 63;
  int e = blockIdx.x;
  int c = min(ccnt[e], 192);
  #pragma unroll
  for (int p = 0; p < 16; ++p) {
    int j = t + p * 512;
    int h = j >> 6, d = j & 63;
    Wt[d * 129 + h] = W1[h * 128 + 64 + d];
  }
  if (t < 128) w2l[t] = W2[t];
  if (t < 96) ((uint*)cls)[t] = ((const uint*)(clist + (size_t)e * 192))[t];
  __syncthreads();
  // pass 1: ef gather, tiered 8/4/1-deep batching
  {
    float a0 = 0.f, a1 = 0.f, a2 = 0.f, a3 = 0.f;
    int j = wv;
    for (; j + 56 < c; j += 64) {
      int n0 = cls[j], n1 = cls[j + 8], n2 = cls[j + 16], n3 = cls[j + 24];
      int n4 = cls[j + 32], n5 = cls[j + 40], n6 = cls[j + 48], n7 = cls[j + 56];
      a0 += x[(size_t)n0 * 64 + lane];
      a1 += x[(size_t)n1 * 64 + lane];
      a2 += x[(size_t)n2 * 64 + lane];
      a3 += x[(size_t)n3 * 64 + lane];
      a0 += x[(size_t)n4 * 64 + lane];
      a1 += x[(size_t)n5 * 64 + lane];
      a2 += x[(size_t)n6 * 64 + lane];
      a3 += x[(size_t)n7 * 64 + lane];
    }
    for (; j + 24 < c; j += 32) {
      int n0 = cls[j], n1 = cls[j + 8], n2 = cls[j + 16], n3 = cls[j + 24];
      a0 += x[(size_t)n0 * 64 + lane];
      a1 += x[(size_t)n1 * 64 + lane];
      a2 += x[(size_t)n2 * 64 + lane];
      a3 += x[(size_t)n3 * 64 + lane];
    }
    for (; j < c; j += 8) a0 += x[(size_t)cls[j] * 64 + lane];
    psum[wv][lane] = (a0 + a1) + (a2 + a3);
  }
  __syncthreads();
  if (wv == 0) {
    float s = 0.f;
    #pragma unroll
    for (int u = 0; u < 8; ++u) s += psum[u][lane];
    efl[lane] = s;
  }
  __syncthreads();
  // projection: 512 threads = 128 h x 4 d-quarters (Wt from LDS)
  {
    int h = t & 127, q = t >> 7;
    float a = 0.f;
    #pragma unroll
    for (int d = q * 16; d < q * 16 + 16; ++d)
      a += efl[d] * Wt[d * 129 + h];
    pp[q][h] = a;
  }
  __syncthreads();
  if (t < 128) epl[t] = pp[0][t] + pp[1][t] + pp[2][t] + pp[3][t];
  __syncthreads();
  // batched scores: 128 entries x 4 subs (32 h each); sigma -> sigc column
  {
    int sub = t & 3, jloc = t >> 2;
    float b2v = b2[0];
    int nb = (c + 127) >> 7;
    for (int b = 0; b < nb; ++b) {
      int j = b * 128 + jloc;
      if (j < c) {
        int n = cls[j];
        const float* npr = npb + (size_t)n * 128;
        float a = 0.f;
        #pragma unroll
        for (int q = 0; q < 8; ++q) {
          int o = q * 16 + sub * 4;
          float4 av = *(const float4*)&npr[o];
          float4 ev = *(const float4*)&epl[o];
          float4 w2 = *(const float4*)&w2l[o];
          a += fmaxf(av.x + ev.x, 0.f) * w2.x + fmaxf(av.y + ev.y, 0.f) * w2.y
             + fmaxf(av.z + ev.z, 0.f) * w2.z + fmaxf(av.w + ev.w, 0.f) * w2.w;
        }
        a += __shfl_xor(a, 1, 64);
        a += __shfl_xor(a, 2, 64);
        if (sub == 0) {
          float sg = 1.f / (1.f + __expf(-(a + b2v)));
          sval[j] = dn[n] * sg;
          sigc[(size_t)e * NN + n] = sg;   // block-local lines only
        }
      }
    }
  }
  __syncthreads();
  // pass 2: weighted gather, tiered 8/4/1-deep batching
  {
    float a0 = 0.f, a1 = 0.f, a2 = 0.f, a3 = 0.f;
    int j = wv;
    for (; j + 56 < c; j += 64) {
      int n0 = cls[j], n1 = cls[j + 8], n2 = cls[j + 16], n3 = cls[j + 24];
      int n4 = cls[j + 32], n5 = cls[j + 40], n6 = cls[j + 48], n7 = cls[j + 56];
      a0 += sval[j] * x[(size_t)n0 * 64 + lane];
      a1 += sval[j + 8] * x[(size_t)n1 * 64 + lane];
      a2 += sval[j + 16] * x[(size_t)n2 * 64 + lane];
      a3 += sval[j + 24] * x[(size_t)n3 * 64 + lane];
      a0 += sval[j + 32] * x[(size_t)n4 * 64 + lane];
      a1 += sval[j + 40] * x[(size_t)n5 * 64 + lane];
      a2 += sval[j + 48] * x[(size_t)n6 * 64 + lane];
      a3 += sval[j + 56] * x[(size_t)n7 * 64 + lane];
    }
    for (; j + 24 < c; j += 32) {
      int n0 = cls[j], n1 = cls[j + 8], n2 = cls[j + 16], n3 = cls[j + 24];
      a0 += sval[j] * x[(size_t)n0 * 64 + lane];
      a1 += sval[j + 8] * x[(size_t)n1 * 64 + lane];
      a2 += sval[j + 16] * x[(size_t)n2 * 64 + lane];
      a3 += sval[j + 24] * x[(size_t)n3 * 64 + lane];
    }
    for (; j < c; j += 8) a0 += sval[j] * x[(size_t)cls[j] * 64 + lane];
    psum[wv][lane] = (a0 + a1) + (a2 + a3);
  }
  __syncthreads();
  if (wv == 0) {
    float s = 0.f;
    #pragma unroll
    for (int u = 0; u < 8; ++u) s += psum[u][lane];
    w[(size_t)e * 64 + lane] = de[e] * s;
  }
}

// ---------------------------------------------------------------------------
// D3 k_node (grid NN/2 x 512): R22 proven structure unchanged.
// ---------------------------------------------------------------------------
__global__ __launch_bounds__(512)
void k_node(const ushortt* __restrict__ elist, const int* __restrict__ cnt,
            const float* __restrict__ dn, const float* __restrict__ sigc,
            const float* __restrict__ w,
            const float* __restrict__ Wlg, const float* __restrict__ bl,
            float* __restrict__ out) {
  __shared__ __align__(16) float Wlds[64 * 65];
  __shared__ __align__(16) float sval[2][128];
  __shared__ __align__(16) float psum[8][64];
  __shared__ __align__(16) float zl[2][64];
  __shared__ __align__(16) ushortt els[2][128];
  int t = threadIdx.x, wv = t >> 6, lane = t & 63;
  int n0 = blockIdx.x * 2;
  #pragma unroll
  for (int p = 0; p < 8; ++p) {
    int j = t + p * 512;
    Wlds[(j >> 6) * 65 + (j & 63)] = Wlg[j];
  }
  if (t < 128) ((uint*)els)[t] = ((const uint*)(elist + (size_t)n0 * 128))[t];
  __syncthreads();
  // sigma gather: one independent load per entry
  if (t < 256) {
    int nd = t >> 7, jj = t & 127;
    int n = n0 + nd;
    int c = min(cnt[n], 128);
    if (jj < c) {
      int e = els[nd][jj];
      sval[nd][jj] = sigc[(size_t)e * NN + n];
    }
  }
  __syncthreads();
  // z gather: waves 0-3 node 0, 4-7 node 1; tiered 8/4/1-deep batching
  {
    int nd = wv >> 2;
    int n = n0 + nd;
    int c = min(cnt[n], 128);
    float a0 = 0.f, a1 = 0.f, a2 = 0.f, a3 = 0.f;
    int j = wv & 3;
    for (; j + 28 < c; j += 32) {
      int e0 = els[nd][j], e1 = els[nd][j + 4], e2 = els[nd][j + 8], e3 = els[nd][j + 12];
      int e4 = els[nd][j + 16], e5 = els[nd][j + 20], e6 = els[nd][j + 24], e7 = els[nd][j + 28];
      a0 += sval[nd][j] * w[(size_t)e0 * 64 + lane];
      a1 += sval[nd][j + 4] * w[(size_t)e1 * 64 + lane];
      a2 += sval[nd][j + 8] * w[(size_t)e2 * 64 + lane];
      a3 += sval[nd][j + 12] * w[(size_t)e3 * 64 + lane];
      a0 += sval[nd][j + 16] * w[(size_t)e4 * 64 + lane];
      a1 += sval[nd][j + 20] * w[(size_t)e5 * 64 + lane];
      a2 += sval[nd][j + 24] * w[(size_t)e6 * 64 + lane];
      a3 += sval[nd][j + 28] * w[(size_t)e7 * 64 + lane];
    }
    for (; j + 12 < c; j += 16) {
      int e0 = els[nd][j], e1 = els[nd][j + 4], e2 = els[nd][j + 8], e3 = els[nd][j + 12];
      a0 += sval[nd][j] * w[(size_t)e0 * 64 + lane];
      a1 += sval[nd][j + 4] * w[(size_t)e1 * 64 + lane];
      a2 += sval[nd][j + 8] * w[(size_t)e2 * 64 + lane];
      a3 += sval[nd][j + 12] * w[(size_t)e3 * 64 + lane];
    }
    for (; j < c; j += 4) a0 += sval[nd][j] * w[(size_t)els[nd][j] * 64 + lane];
    psum[wv][lane] = (a0 + a1) + (a2 + a3);
    __syncthreads();
    if ((wv & 3) == 0)
      zl[nd][lane] = dn[n] * (psum[wv][lane] + psum[wv + 1][lane] +
                              psum[wv + 2][lane] + psum[wv + 3][lane]);
  }
  __syncthreads();
  {
    float* pp = (float*)psum;
    int o = t & 63, nd = (t >> 6) & 1, q = t >> 7;
    float po = 0.f;
    #pragma unroll
    for (int d = q * 16; d < q * 16 + 16; ++d)
      po += zl[nd][d] * Wlds[o * 65 + d];
    pp[q * 128 + nd * 64 + o] = po;
    __syncthreads();
    if (t < 128) {
      int ndo = t >> 6, oo = t & 63;
      out[(size_t)(n0 + ndo) * 64 + oo] =
          bl[oo] + pp[0 * 128 + t] + pp[1 * 128 + t] + pp[2 * 128 + t] + pp[3 * 128 + t];
    }
  }
}

extern "C" void kernel_launch(void* const* d_in, const int* in_sizes, int n_in,
                              void* d_out, int out_size, void* d_ws, size_t ws_size,
                              hipStream_t stream) {
  const float* x  = (const float*)d_in[0];
  const float* H  = (const float*)d_in[1];
  const float* W1 = (const float*)d_in[2];
  const float* b1 = (const float*)d_in[3];
  const float* W2 = (const float*)d_in[4];
  const float* b2 = (const float*)d_in[5];
  const float* Wl = (const float*)d_in[6];
  const float* bl = (const float*)d_in[7];
  float* out = (float*)d_out;

  char* wsb = (char*)d_ws;
  float* dn   = (float*)wsb;  wsb += NN * 4;
  float* de   = (float*)wsb;  wsb += EE * 4;
  int*   cnt  = (int*)wsb;    wsb += NN * 4;
  int*   ccnt = (int*)wsb;    wsb += EE * 4;
  float* npb  = (float*)wsb;  wsb += (size_t)NN * 128 * 4;
  float* w    = (float*)wsb;  wsb += (size_t)EE * 64 * 4;
  float* sigc = (float*)wsb;  wsb += (size_t)EE * NN * 4;  // nnz-only, col-major
  ushortt* elist = (ushortt*)wsb; wsb += (size_t)NN * 128 * 2;
  ushortt* clist = (ushortt*)wsb; wsb += (size_t)EE * 192 * 2;

  hipLaunchKernelGGL(k_scan, dim3(640), dim3(512), 0, stream,
                     H, x, W1, b1, elist, cnt, dn, clist, ccnt, de, npb);
  hipLaunchKernelGGL(k_edge, dim3(EE), dim3(512), 0, stream,
                     clist, ccnt, de, dn, x, W1, npb, W2, b2, sigc, w);
  hipLaunchKernelGGL(k_node, dim3(NN / 2), dim3(512), 0, stream,
                     elist, cnt, dn, sigc, w, Wl, bl, out);
}